// Round 8
// baseline (140.783 us; speedup 1.0000x reference)
//
#include <hip/hip_runtime.h>

constexpr int D = 128;

using short8 = __attribute__((ext_vector_type(8))) short;
using f32x4  = __attribute__((ext_vector_type(4))) float;
using uint4v = __attribute__((ext_vector_type(4))) unsigned int;

__device__ inline unsigned short f2bf(float f) {
    unsigned u = __float_as_uint(f);
    u = (u + 0x7FFFu + ((u >> 16) & 1u)) >> 16;   // RN-even
    return (unsigned short)u;
}

// ---------------- CSR-build scans (counts from degree; no hist) ----------------

__global__ __launch_bounds__(256) void scan_partial_kernel(
    const float* __restrict__ degree, int* __restrict__ bsum, int N)
{
    __shared__ int a[256];
    int i = blockIdx.x * 256 + threadIdx.x;
    a[threadIdx.x] = (i < N) ? (int)degree[i] : 0;
    __syncthreads();
    for (int off = 128; off > 0; off >>= 1) {
        if (threadIdx.x < off) a[threadIdx.x] += a[threadIdx.x + off];
        __syncthreads();
    }
    if (threadIdx.x == 0) bsum[blockIdx.x] = a[0];
}

__global__ __launch_bounds__(256) void scan_offsets_kernel(
    const float* __restrict__ degree, const int* __restrict__ bsum,
    int* __restrict__ starts, int* __restrict__ work, int N)
{
    __shared__ int a[256], b2[256];
    __shared__ int prefix_s;
    const int t = threadIdx.x;
    const int i = blockIdx.x * 256 + t;

    int p = 0;
    for (int j = t; j < blockIdx.x; j += 256) p += bsum[j];
    a[t] = p;
    __syncthreads();
    for (int off = 128; off > 0; off >>= 1) {
        if (t < off) a[t] += a[t + off];
        __syncthreads();
    }
    if (t == 0) prefix_s = a[0];
    __syncthreads();
    const int prefix = prefix_s;
    __syncthreads();

    const int v = (i < N) ? (int)degree[i] : 0;
    a[t] = v;
    __syncthreads();
    int* cur = a; int* nxt = b2;
    for (int off = 1; off < 256; off <<= 1) {
        int x = cur[t];
        if (t >= off) x += cur[t - off];
        nxt[t] = x;
        __syncthreads();
        int* tmp = cur; cur = nxt; nxt = tmp;
    }
    if (i < N) {
        const int val = prefix + cur[t] - v;   // exclusive
        starts[i] = val;
        work[i]   = val;
    }
}

// ---------------- fused: bucket scatter + GEMM (independent work, one kernel) ----
// blocks [0, nbucket): bucket; blocks [nbucket, nbucket+ngemm): y = bf16(x)@bf16(W).
// GEMM W-frags read straight from global (L2-hot, 64 KB) -> no LDS -> high occupancy.
__global__ __launch_bounds__(512) void bucket_gemm_kernel(
    const int* __restrict__ src, const int* __restrict__ dst,
    int* __restrict__ work, int* __restrict__ edge_src, int E, int nbucket,
    const float* __restrict__ x, const float* __restrict__ W,
    unsigned short* __restrict__ y, int N, int ngemm)
{
    if (blockIdx.x < nbucket) {
        int e = blockIdx.x * 512 + threadIdx.x;
        if (e < E) {
            int pos = atomicAdd(&work[dst[e]], 1);
            edge_src[pos] = src[e];
        }
        return;
    }

    const int bid  = blockIdx.x - nbucket;
    const int tid  = threadIdx.x;
    const int l    = tid & 63;
    const int wave = tid >> 6;
    const int wr   = wave >> 1;          // 0..3 row sub-tile
    const int wc   = wave & 1;           // 0..1 col half
    const int lcol = l & 15;
    const int lk   = (l >> 4) * 8;

    short8 Bf[4][4];
    #pragma unroll
    for (int c = 0; c < 4; ++c) {
        const int col = wc * 64 + c * 16 + lcol;
        #pragma unroll
        for (int ks = 0; ks < 4; ++ks) {
            #pragma unroll
            for (int j = 0; j < 8; ++j)
                Bf[c][ks][j] = (short)f2bf(W[(ks * 32 + lk + j) * D + col]);
        }
    }

    for (int r0 = bid * 64 + wr * 16; r0 < N; r0 += ngemm * 64) {
        const int arow = r0 + lcol;
        short8 Af[4];
        if (arow < N) {
            #pragma unroll
            for (int ks = 0; ks < 4; ++ks) {
                const float4 a0 = *(const float4*)(x + (size_t)arow * D + ks * 32 + lk);
                const float4 a1 = *(const float4*)(x + (size_t)arow * D + ks * 32 + lk + 4);
                Af[ks][0] = (short)f2bf(a0.x); Af[ks][1] = (short)f2bf(a0.y);
                Af[ks][2] = (short)f2bf(a0.z); Af[ks][3] = (short)f2bf(a0.w);
                Af[ks][4] = (short)f2bf(a1.x); Af[ks][5] = (short)f2bf(a1.y);
                Af[ks][6] = (short)f2bf(a1.z); Af[ks][7] = (short)f2bf(a1.w);
            }
        } else {
            #pragma unroll
            for (int ks = 0; ks < 4; ++ks) Af[ks] = short8{0,0,0,0,0,0,0,0};
        }

        #pragma unroll
        for (int c = 0; c < 4; ++c) {
            f32x4 acc = {0.f, 0.f, 0.f, 0.f};
            #pragma unroll
            for (int ks = 0; ks < 4; ++ks)
                acc = __builtin_amdgcn_mfma_f32_16x16x32_bf16(Af[ks], Bf[c][ks], acc, 0, 0, 0);
            const int col = wc * 64 + c * 16 + lcol;
            #pragma unroll
            for (int q = 0; q < 4; ++q) {
                const int row = r0 + (l >> 4) * 4 + q;
                if (row < N) y[(size_t)row * D + col] = f2bf(acc[q]);
            }
        }
    }
}

// ---------------- aggregate v3: out[n] = (sum y[src])/deg + b ----------------
// Wave handles npw consecutive nodes; its edge window is CONTIGUOUS
// [starts[nb], work[ne-1]) -> staged into LDS once (coalesced), gather
// addresses then come from LDS broadcasts. 4 slots x (2 explicit + unroll 2)
// = 4 gathers in flight per lane, nontemporal.
__global__ __launch_bounds__(256) void aggregate_y3_kernel(
    const unsigned short* __restrict__ y, const int* __restrict__ edge_src,
    const int* __restrict__ starts, const int* __restrict__ work,
    const float* __restrict__ degree, const float* __restrict__ bias,
    float* __restrict__ out, int N, int npw)
{
    __shared__ int elds[4][512];
    const int wid  = threadIdx.x >> 6;
    const int lane = threadIdx.x & 63;
    const int g = lane >> 4;            // edge slot 0..3
    const int t = lane & 15;            // col group
    const size_t coff = (size_t)t * 8;

    const long long w = (long long)blockIdx.x * 4 + wid;
    int nb = (int)(w * npw);
    if (nb >= N) return;
    const int ne = (nb + npw < N) ? nb + npw : N;

    const float4 bq = *(const float4*)(bias + coff + (g & 1) * 4);

    const int estart = starts[nb];
    const int eend   = work[ne - 1];
    const int ecnt   = eend - estart;
    const bool staged = (ecnt <= 512);
    if (staged) {
        for (int j = lane; j < ecnt; j += 64)
            elds[wid][j] = edge_src[estart + j];
    }

    for (int n = nb; n < ne; ++n) {
        const int beg = starts[n];
        const int end = work[n];
        const int cnt = end - beg;

        float ax[8];
        #pragma unroll
        for (int k = 0; k < 8; ++k) ax[k] = 0.f;

        if (staged) {
            const int b0 = beg - estart;
            int i = g;
            #pragma unroll 2
            for (; i + 4 < cnt; i += 8) {
                const int s0 = elds[wid][b0 + i];
                const int s1 = elds[wid][b0 + i + 4];
                const uint4v v0 = __builtin_nontemporal_load(
                    (const uint4v*)(y + (size_t)s0 * D + coff));
                const uint4v v1 = __builtin_nontemporal_load(
                    (const uint4v*)(y + (size_t)s1 * D + coff));
                #pragma unroll
                for (int k = 0; k < 4; ++k) {
                    ax[2 * k]     += __uint_as_float(v0[k] << 16)
                                   + __uint_as_float(v1[k] << 16);
                    ax[2 * k + 1] += __uint_as_float(v0[k] & 0xFFFF0000u)
                                   + __uint_as_float(v1[k] & 0xFFFF0000u);
                }
            }
            for (; i < cnt; i += 4) {
                const int s0 = elds[wid][b0 + i];
                const uint4v v0 = __builtin_nontemporal_load(
                    (const uint4v*)(y + (size_t)s0 * D + coff));
                #pragma unroll
                for (int k = 0; k < 4; ++k) {
                    ax[2 * k]     += __uint_as_float(v0[k] << 16);
                    ax[2 * k + 1] += __uint_as_float(v0[k] & 0xFFFF0000u);
                }
            }
        } else {
            int i = g;
            #pragma unroll 2
            for (; i + 4 < cnt; i += 8) {
                const int s0 = edge_src[beg + i];
                const int s1 = edge_src[beg + i + 4];
                const uint4v v0 = __builtin_nontemporal_load(
                    (const uint4v*)(y + (size_t)s0 * D + coff));
                const uint4v v1 = __builtin_nontemporal_load(
                    (const uint4v*)(y + (size_t)s1 * D + coff));
                #pragma unroll
                for (int k = 0; k < 4; ++k) {
                    ax[2 * k]     += __uint_as_float(v0[k] << 16)
                                   + __uint_as_float(v1[k] << 16);
                    ax[2 * k + 1] += __uint_as_float(v0[k] & 0xFFFF0000u)
                                   + __uint_as_float(v1[k] & 0xFFFF0000u);
                }
            }
            for (; i < cnt; i += 4) {
                const int s0 = edge_src[beg + i];
                const uint4v v0 = __builtin_nontemporal_load(
                    (const uint4v*)(y + (size_t)s0 * D + coff));
                #pragma unroll
                for (int k = 0; k < 4; ++k) {
                    ax[2 * k]     += __uint_as_float(v0[k] << 16);
                    ax[2 * k + 1] += __uint_as_float(v0[k] & 0xFFFF0000u);
                }
            }
        }

        #pragma unroll
        for (int k = 0; k < 8; ++k) {
            ax[k] += __shfl_xor(ax[k], 16, 64);
            ax[k] += __shfl_xor(ax[k], 32, 64);
        }

        if (g < 2) {
            const float invd = 1.0f / degree[n];
            const int kb = (g & 1) * 4;
            float4 o;
            o.x = ax[kb + 0] * invd + bq.x;
            o.y = ax[kb + 1] * invd + bq.y;
            o.z = ax[kb + 2] * invd + bq.z;
            o.w = ax[kb + 3] * invd + bq.w;
            *(float4*)(out + (size_t)n * D + coff + kb) = o;
        }
    }
}

// ---------------- mid path (fp32 h in d_out) ----------------

__global__ __launch_bounds__(256) void aggregate_f32_kernel(
    const float* __restrict__ inputs, const int* __restrict__ edge_src,
    const int* __restrict__ starts, const int* __restrict__ work,
    const float* __restrict__ degree, float* __restrict__ out, int N)
{
    const int wid = threadIdx.x >> 6;
    const int lane = threadIdx.x & 63;
    const int n = blockIdx.x * 4 + wid;
    if (n >= N) return;
    const int beg = starts[n];
    const int end = work[n];
    const int c = lane * 2;
    float ax = 0.f, ay = 0.f;
    for (int i = beg; i < end; ++i) {
        const float2 v = *(const float2*)(inputs + (size_t)edge_src[i] * D + c);
        ax += v.x;
        ay += v.y;
    }
    const float invd = 1.0f / degree[n];
    float2 r; r.x = ax * invd; r.y = ay * invd;
    *(float2*)(out + (size_t)n * D + c) = r;
}

__global__ __launch_bounds__(256, 4) void transform3_kernel(
    float* __restrict__ out, const float* __restrict__ W,
    const float* __restrict__ b, int N)
{
    __shared__ float Ws[D * D];
    __shared__ float hs[16][D + 4];

    const int tid = threadIdx.x;
    for (int i = tid; i < D * D; i += 256) Ws[i] = W[i];

    const int c0 = (tid & 63) * 2;
    const int rb = (tid >> 6) * 4;
    float2 bias; bias.x = b[c0]; bias.y = b[c0 + 1];
    const int lr = tid >> 4;
    const int lc = (tid & 15) * 8;
    __syncthreads();

    for (int n0 = blockIdx.x * 16; n0 < N; n0 += gridDim.x * 16) {
        const int ln = n0 + lr;
        if (ln < N) {
            *(float4*)&hs[lr][lc]     = *(const float4*)(out + (size_t)ln * D + lc);
            *(float4*)&hs[lr][lc + 4] = *(const float4*)(out + (size_t)ln * D + lc + 4);
        } else {
            const float4 z = make_float4(0.f, 0.f, 0.f, 0.f);
            *(float4*)&hs[lr][lc] = z;
            *(float4*)&hs[lr][lc + 4] = z;
        }
        __syncthreads();

        float2 acc0 = bias, acc1 = bias, acc2 = bias, acc3 = bias;
        #pragma unroll 2
        for (int k = 0; k < D; k += 4) {
            const float4 h0 = *(const float4*)&hs[rb + 0][k];
            const float4 h1 = *(const float4*)&hs[rb + 1][k];
            const float4 h2 = *(const float4*)&hs[rb + 2][k];
            const float4 h3 = *(const float4*)&hs[rb + 3][k];
            #pragma unroll
            for (int kk = 0; kk < 4; ++kk) {
                const float2 w = *(const float2*)&Ws[(k + kk) * D + c0];
                const float e0 = (kk == 0) ? h0.x : (kk == 1) ? h0.y : (kk == 2) ? h0.z : h0.w;
                const float e1 = (kk == 0) ? h1.x : (kk == 1) ? h1.y : (kk == 2) ? h1.z : h1.w;
                const float e2 = (kk == 0) ? h2.x : (kk == 1) ? h2.y : (kk == 2) ? h2.z : h2.w;
                const float e3 = (kk == 0) ? h3.x : (kk == 1) ? h3.y : (kk == 2) ? h3.z : h3.w;
                acc0.x = fmaf(e0, w.x, acc0.x); acc0.y = fmaf(e0, w.y, acc0.y);
                acc1.x = fmaf(e1, w.x, acc1.x); acc1.y = fmaf(e1, w.y, acc1.y);
                acc2.x = fmaf(e2, w.x, acc2.x); acc2.y = fmaf(e2, w.y, acc2.y);
                acc3.x = fmaf(e3, w.x, acc3.x); acc3.y = fmaf(e3, w.y, acc3.y);
            }
        }
        __syncthreads();

        const int nb = n0 + rb;
        if (nb + 0 < N) *(float2*)(out + (size_t)(nb + 0) * D + c0) = acc0;
        if (nb + 1 < N) *(float2*)(out + (size_t)(nb + 1) * D + c0) = acc1;
        if (nb + 2 < N) *(float2*)(out + (size_t)(nb + 2) * D + c0) = acc2;
        if (nb + 3 < N) *(float2*)(out + (size_t)(nb + 3) * D + c0) = acc3;
    }
}

// ---------------- atomic fallback ----------------

__global__ __launch_bounds__(256) void scatter_kernel(
    const float* __restrict__ inputs, const int* __restrict__ src,
    const int* __restrict__ dst, float* __restrict__ out, long long total_threads)
{
    long long tid = (long long)blockIdx.x * blockDim.x + threadIdx.x;
    if (tid >= total_threads) return;
    int e = (int)(tid >> 5);
    int lane = (int)(tid & 31);
    const float4 v = *(const float4*)(inputs + (size_t)src[e] * D + lane * 4);
    float* op = out + (size_t)dst[e] * D + lane * 4;
    atomicAdd(op + 0, v.x);
    atomicAdd(op + 1, v.y);
    atomicAdd(op + 2, v.z);
    atomicAdd(op + 3, v.w);
}

__global__ __launch_bounds__(256) void divide_kernel(
    float* __restrict__ out, const float* __restrict__ degree, int N)
{
    long long i = (long long)blockIdx.x * 256 + threadIdx.x;
    if (i < (long long)N * D) out[i] /= degree[i >> 7];
}

extern "C" void kernel_launch(void* const* d_in, const int* in_sizes, int n_in,
                              void* d_out, int out_size, void* d_ws, size_t ws_size,
                              hipStream_t stream) {
    const float* inputs = (const float*)d_in[0];
    const int*   src    = (const int*)d_in[1];
    const int*   dst    = (const int*)d_in[2];
    const float* degree = (const float*)d_in[3];
    const float* W      = (const float*)d_in[4];
    const float* b      = (const float*)d_in[5];
    float* out = (float*)d_out;

    const int E = in_sizes[1];
    const int N = in_sizes[3];
    const int nscan = (N + 255) / 256;

    // ws layout: starts[N] | work[N] | bsum[512] | edge_src[E+N] | (align16) y_bf16[N*D]
    const size_t ints_csr  = (size_t)3 * N + 512 + E;
    const size_t y_off     = ((ints_csr * 4) + 15) & ~(size_t)15;
    const size_t needed_full = y_off + (size_t)N * D * 2;
    const size_t needed_csr  = ints_csr * 4;

    if (ws_size >= needed_full && nscan <= 4096) {
        int* starts   = (int*)d_ws;
        int* work     = starts + N;
        int* bsum     = work + N;
        int* edge_src = bsum + 512;
        unsigned short* ybf = (unsigned short*)((char*)d_ws + y_off);

        scan_partial_kernel<<<nscan, 256, 0, stream>>>(degree, bsum, N);
        scan_offsets_kernel<<<nscan, 256, 0, stream>>>(degree, bsum, starts, work, N);

        const int nbucket = (E + 511) / 512;
        const int ngemm   = 512;
        bucket_gemm_kernel<<<nbucket + ngemm, 512, 0, stream>>>(
            src, dst, work, edge_src, E, nbucket, inputs, W, ybf, N, ngemm);

        const int npw = (N + 8191) / 8192;                 // ~13 nodes per wave
        const int nwaves = (N + npw - 1) / npw;
        aggregate_y3_kernel<<<(nwaves + 3) / 4, 256, 0, stream>>>(
            ybf, edge_src, starts, work, degree, b, out, N, npw);
    } else if (ws_size >= needed_csr && nscan <= 4096) {
        int* starts   = (int*)d_ws;
        int* work     = starts + N;
        int* bsum     = work + N;
        int* edge_src = bsum + 512;

        scan_partial_kernel<<<nscan, 256, 0, stream>>>(degree, bsum, N);
        scan_offsets_kernel<<<nscan, 256, 0, stream>>>(degree, bsum, starts, work, N);
        // bucket via fused kernel with ngemm=0
        const int nbucket = (E + 511) / 512;
        bucket_gemm_kernel<<<nbucket, 512, 0, stream>>>(
            src, dst, work, edge_src, E, nbucket, inputs, W, nullptr, 0, 1);
        aggregate_f32_kernel<<<(N + 3) / 4, 256, 0, stream>>>(
            inputs, edge_src, starts, work, degree, out, N);
        transform3_kernel<<<2048, 256, 0, stream>>>(out, W, b, N);
    } else {
        hipMemsetAsync(d_out, 0, (size_t)N * D * sizeof(float), stream);
        const long long total = (long long)E * 32;
        scatter_kernel<<<(int)((total + 255) / 256), 256, 0, stream>>>(inputs, src, dst, out, total);
        divide_kernel<<<(int)(((long long)N * D + 255) / 256), 256, 0, stream>>>(out, degree, N);
        transform3_kernel<<<2048, 256, 0, stream>>>(out, W, b, N);
    }
}

// Round 9
// 105.909 us; speedup vs baseline: 1.3293x; 1.3293x over previous
//
#include <hip/hip_runtime.h>

constexpr int D = 128;

using short8 = __attribute__((ext_vector_type(8))) short;
using f32x4  = __attribute__((ext_vector_type(4))) float;

__device__ inline unsigned short f2bf(float f) {
    unsigned u = __float_as_uint(f);
    u = (u + 0x7FFFu + ((u >> 16) & 1u)) >> 16;   // RN-even
    return (unsigned short)u;
}

// ---------------- CSR-build scans (counts from degree; no hist) ----------------

__global__ __launch_bounds__(256) void scan_partial_kernel(
    const float* __restrict__ degree, int* __restrict__ bsum, int N)
{
    __shared__ int a[256];
    int i = blockIdx.x * 256 + threadIdx.x;
    a[threadIdx.x] = (i < N) ? (int)degree[i] : 0;
    __syncthreads();
    for (int off = 128; off > 0; off >>= 1) {
        if (threadIdx.x < off) a[threadIdx.x] += a[threadIdx.x + off];
        __syncthreads();
    }
    if (threadIdx.x == 0) bsum[blockIdx.x] = a[0];
}

__global__ __launch_bounds__(256) void scan_offsets_kernel(
    const float* __restrict__ degree, const int* __restrict__ bsum,
    int* __restrict__ starts, int* __restrict__ work, int N)
{
    __shared__ int a[256], b2[256];
    __shared__ int prefix_s;
    const int t = threadIdx.x;
    const int i = blockIdx.x * 256 + t;

    int p = 0;
    for (int j = t; j < blockIdx.x; j += 256) p += bsum[j];
    a[t] = p;
    __syncthreads();
    for (int off = 128; off > 0; off >>= 1) {
        if (t < off) a[t] += a[t + off];
        __syncthreads();
    }
    if (t == 0) prefix_s = a[0];
    __syncthreads();
    const int prefix = prefix_s;
    __syncthreads();

    const int v = (i < N) ? (int)degree[i] : 0;
    a[t] = v;
    __syncthreads();
    int* cur = a; int* nxt = b2;
    for (int off = 1; off < 256; off <<= 1) {
        int x = cur[t];
        if (t >= off) x += cur[t - off];
        nxt[t] = x;
        __syncthreads();
        int* tmp = cur; cur = nxt; nxt = tmp;
    }
    if (i < N) {
        const int val = prefix + cur[t] - v;   // exclusive
        starts[i] = val;
        work[i]   = val;
    }
}

// ---------------- fused: bucket scatter + GEMM (independent work, one kernel) ----
// blocks [0, nbucket): bucket; blocks [nbucket, nbucket+ngemm): y = bf16(x)@bf16(W).
__global__ __launch_bounds__(512) void bucket_gemm_kernel(
    const int* __restrict__ src, const int* __restrict__ dst,
    int* __restrict__ work, int* __restrict__ edge_src, int E, int nbucket,
    const float* __restrict__ x, const float* __restrict__ W,
    unsigned short* __restrict__ y, int N, int ngemm)
{
    if (blockIdx.x < nbucket) {
        int e = blockIdx.x * 512 + threadIdx.x;
        if (e < E) {
            int pos = atomicAdd(&work[dst[e]], 1);
            edge_src[pos] = src[e];
        }
        return;
    }

    const int bid  = blockIdx.x - nbucket;
    const int tid  = threadIdx.x;
    const int l    = tid & 63;
    const int wave = tid >> 6;
    const int wr   = wave >> 1;          // 0..3 row sub-tile
    const int wc   = wave & 1;           // 0..1 col half
    const int lcol = l & 15;
    const int lk   = (l >> 4) * 8;

    short8 Bf[4][4];
    #pragma unroll
    for (int c = 0; c < 4; ++c) {
        const int col = wc * 64 + c * 16 + lcol;
        #pragma unroll
        for (int ks = 0; ks < 4; ++ks) {
            #pragma unroll
            for (int j = 0; j < 8; ++j)
                Bf[c][ks][j] = (short)f2bf(W[(ks * 32 + lk + j) * D + col]);
        }
    }

    for (int r0 = bid * 64 + wr * 16; r0 < N; r0 += ngemm * 64) {
        const int arow = r0 + lcol;
        short8 Af[4];
        if (arow < N) {
            #pragma unroll
            for (int ks = 0; ks < 4; ++ks) {
                const float4 a0 = *(const float4*)(x + (size_t)arow * D + ks * 32 + lk);
                const float4 a1 = *(const float4*)(x + (size_t)arow * D + ks * 32 + lk + 4);
                Af[ks][0] = (short)f2bf(a0.x); Af[ks][1] = (short)f2bf(a0.y);
                Af[ks][2] = (short)f2bf(a0.z); Af[ks][3] = (short)f2bf(a0.w);
                Af[ks][4] = (short)f2bf(a1.x); Af[ks][5] = (short)f2bf(a1.y);
                Af[ks][6] = (short)f2bf(a1.z); Af[ks][7] = (short)f2bf(a1.w);
            }
        } else {
            #pragma unroll
            for (int ks = 0; ks < 4; ++ks) Af[ks] = short8{0,0,0,0,0,0,0,0};
        }

        #pragma unroll
        for (int c = 0; c < 4; ++c) {
            f32x4 acc = {0.f, 0.f, 0.f, 0.f};
            #pragma unroll
            for (int ks = 0; ks < 4; ++ks)
                acc = __builtin_amdgcn_mfma_f32_16x16x32_bf16(Af[ks], Bf[c][ks], acc, 0, 0, 0);
            const int col = wc * 64 + c * 16 + lcol;
            #pragma unroll
            for (int q = 0; q < 4; ++q) {
                const int row = r0 + (l >> 4) * 4 + q;
                if (row < N) y[(size_t)row * D + col] = f2bf(acc[q]);
            }
        }
    }
}

// ---------------- aggregate: out[n] = (sum y[src])/deg + b ----------------
// One wave per node (measured-best structure, r6: 44 µs). 16 lanes/row
// (uint4 = 8 bf16), 4 edge slots per wave-load; shfl_xor(16,32) reduce;
// fused bias; fp32 out.
__global__ __launch_bounds__(256) void aggregate_y4_kernel(
    const unsigned short* __restrict__ y, const int* __restrict__ edge_src,
    const int* __restrict__ starts, const int* __restrict__ work,
    const float* __restrict__ degree, const float* __restrict__ bias,
    float* __restrict__ out, int N)
{
    const int wid  = threadIdx.x >> 6;
    const int lane = threadIdx.x & 63;
    const int n = blockIdx.x * 4 + wid;
    if (n >= N) return;
    const int beg = starts[n];
    const int end = work[n];
    const int g = lane >> 4;            // edge slot 0..3
    const int t = lane & 15;            // col group: cols t*8 .. t*8+7
    const size_t coff = (size_t)t * 8;

    const float4 bq = *(const float4*)(bias + coff + (g & 1) * 4);

    float ax[8];
    #pragma unroll
    for (int k = 0; k < 8; ++k) ax[k] = 0.f;

    #pragma unroll 2
    for (int i = beg; i < end; i += 4) {
        const int ii = i + g;
        if (ii < end) {
            const int s = edge_src[ii];
            const uint4 v = *(const uint4*)(y + (size_t)s * D + coff);
            ax[0] += __uint_as_float(v.x << 16);
            ax[1] += __uint_as_float(v.x & 0xFFFF0000u);
            ax[2] += __uint_as_float(v.y << 16);
            ax[3] += __uint_as_float(v.y & 0xFFFF0000u);
            ax[4] += __uint_as_float(v.z << 16);
            ax[5] += __uint_as_float(v.z & 0xFFFF0000u);
            ax[6] += __uint_as_float(v.w << 16);
            ax[7] += __uint_as_float(v.w & 0xFFFF0000u);
        }
    }

    #pragma unroll
    for (int k = 0; k < 8; ++k) {
        ax[k] += __shfl_xor(ax[k], 16, 64);
        ax[k] += __shfl_xor(ax[k], 32, 64);
    }

    if (g < 2) {
        const float invd = 1.0f / degree[n];
        const int kb = (g & 1) * 4;
        float4 o;
        o.x = ax[kb + 0] * invd + bq.x;
        o.y = ax[kb + 1] * invd + bq.y;
        o.z = ax[kb + 2] * invd + bq.z;
        o.w = ax[kb + 3] * invd + bq.w;
        *(float4*)(out + (size_t)n * D + coff + kb) = o;
    }
}

// ---------------- mid path (fp32 h in d_out) ----------------

__global__ __launch_bounds__(256) void aggregate_f32_kernel(
    const float* __restrict__ inputs, const int* __restrict__ edge_src,
    const int* __restrict__ starts, const int* __restrict__ work,
    const float* __restrict__ degree, float* __restrict__ out, int N)
{
    const int wid = threadIdx.x >> 6;
    const int lane = threadIdx.x & 63;
    const int n = blockIdx.x * 4 + wid;
    if (n >= N) return;
    const int beg = starts[n];
    const int end = work[n];
    const int c = lane * 2;
    float ax = 0.f, ay = 0.f;
    for (int i = beg; i < end; ++i) {
        const float2 v = *(const float2*)(inputs + (size_t)edge_src[i] * D + c);
        ax += v.x;
        ay += v.y;
    }
    const float invd = 1.0f / degree[n];
    float2 r; r.x = ax * invd; r.y = ay * invd;
    *(float2*)(out + (size_t)n * D + c) = r;
}

__global__ __launch_bounds__(256, 4) void transform3_kernel(
    float* __restrict__ out, const float* __restrict__ W,
    const float* __restrict__ b, int N)
{
    __shared__ float Ws[D * D];
    __shared__ float hs[16][D + 4];

    const int tid = threadIdx.x;
    for (int i = tid; i < D * D; i += 256) Ws[i] = W[i];

    const int c0 = (tid & 63) * 2;
    const int rb = (tid >> 6) * 4;
    float2 bias; bias.x = b[c0]; bias.y = b[c0 + 1];
    const int lr = tid >> 4;
    const int lc = (tid & 15) * 8;
    __syncthreads();

    for (int n0 = blockIdx.x * 16; n0 < N; n0 += gridDim.x * 16) {
        const int ln = n0 + lr;
        if (ln < N) {
            *(float4*)&hs[lr][lc]     = *(const float4*)(out + (size_t)ln * D + lc);
            *(float4*)&hs[lr][lc + 4] = *(const float4*)(out + (size_t)ln * D + lc + 4);
        } else {
            const float4 z = make_float4(0.f, 0.f, 0.f, 0.f);
            *(float4*)&hs[lr][lc] = z;
            *(float4*)&hs[lr][lc + 4] = z;
        }
        __syncthreads();

        float2 acc0 = bias, acc1 = bias, acc2 = bias, acc3 = bias;
        #pragma unroll 2
        for (int k = 0; k < D; k += 4) {
            const float4 h0 = *(const float4*)&hs[rb + 0][k];
            const float4 h1 = *(const float4*)&hs[rb + 1][k];
            const float4 h2 = *(const float4*)&hs[rb + 2][k];
            const float4 h3 = *(const float4*)&hs[rb + 3][k];
            #pragma unroll
            for (int kk = 0; kk < 4; ++kk) {
                const float2 w = *(const float2*)&Ws[(k + kk) * D + c0];
                const float e0 = (kk == 0) ? h0.x : (kk == 1) ? h0.y : (kk == 2) ? h0.z : h0.w;
                const float e1 = (kk == 0) ? h1.x : (kk == 1) ? h1.y : (kk == 2) ? h1.z : h1.w;
                const float e2 = (kk == 0) ? h2.x : (kk == 1) ? h2.y : (kk == 2) ? h2.z : h2.w;
                const float e3 = (kk == 0) ? h3.x : (kk == 1) ? h3.y : (kk == 2) ? h3.z : h3.w;
                acc0.x = fmaf(e0, w.x, acc0.x); acc0.y = fmaf(e0, w.y, acc0.y);
                acc1.x = fmaf(e1, w.x, acc1.x); acc1.y = fmaf(e1, w.y, acc1.y);
                acc2.x = fmaf(e2, w.x, acc2.x); acc2.y = fmaf(e2, w.y, acc2.y);
                acc3.x = fmaf(e3, w.x, acc3.x); acc3.y = fmaf(e3, w.y, acc3.y);
            }
        }
        __syncthreads();

        const int nb = n0 + rb;
        if (nb + 0 < N) *(float2*)(out + (size_t)(nb + 0) * D + c0) = acc0;
        if (nb + 1 < N) *(float2*)(out + (size_t)(nb + 1) * D + c0) = acc1;
        if (nb + 2 < N) *(float2*)(out + (size_t)(nb + 2) * D + c0) = acc2;
        if (nb + 3 < N) *(float2*)(out + (size_t)(nb + 3) * D + c0) = acc3;
    }
}

// ---------------- atomic fallback ----------------

__global__ __launch_bounds__(256) void scatter_kernel(
    const float* __restrict__ inputs, const int* __restrict__ src,
    const int* __restrict__ dst, float* __restrict__ out, long long total_threads)
{
    long long tid = (long long)blockIdx.x * blockDim.x + threadIdx.x;
    if (tid >= total_threads) return;
    int e = (int)(tid >> 5);
    int lane = (int)(tid & 31);
    const float4 v = *(const float4*)(inputs + (size_t)src[e] * D + lane * 4);
    float* op = out + (size_t)dst[e] * D + lane * 4;
    atomicAdd(op + 0, v.x);
    atomicAdd(op + 1, v.y);
    atomicAdd(op + 2, v.z);
    atomicAdd(op + 3, v.w);
}

__global__ __launch_bounds__(256) void divide_kernel(
    float* __restrict__ out, const float* __restrict__ degree, int N)
{
    long long i = (long long)blockIdx.x * 256 + threadIdx.x;
    if (i < (long long)N * D) out[i] /= degree[i >> 7];
}

extern "C" void kernel_launch(void* const* d_in, const int* in_sizes, int n_in,
                              void* d_out, int out_size, void* d_ws, size_t ws_size,
                              hipStream_t stream) {
    const float* inputs = (const float*)d_in[0];
    const int*   src    = (const int*)d_in[1];
    const int*   dst    = (const int*)d_in[2];
    const float* degree = (const float*)d_in[3];
    const float* W      = (const float*)d_in[4];
    const float* b      = (const float*)d_in[5];
    float* out = (float*)d_out;

    const int E = in_sizes[1];
    const int N = in_sizes[3];
    const int nscan = (N + 255) / 256;

    // ws layout: starts[N] | work[N] | bsum[512] | edge_src[E+N] | (align16) y_bf16[N*D]
    const size_t ints_csr  = (size_t)3 * N + 512 + E;
    const size_t y_off     = ((ints_csr * 4) + 15) & ~(size_t)15;
    const size_t needed_full = y_off + (size_t)N * D * 2;
    const size_t needed_csr  = ints_csr * 4;

    if (ws_size >= needed_full && nscan <= 4096) {
        int* starts   = (int*)d_ws;
        int* work     = starts + N;
        int* bsum     = work + N;
        int* edge_src = bsum + 512;
        unsigned short* ybf = (unsigned short*)((char*)d_ws + y_off);

        scan_partial_kernel<<<nscan, 256, 0, stream>>>(degree, bsum, N);
        scan_offsets_kernel<<<nscan, 256, 0, stream>>>(degree, bsum, starts, work, N);

        const int nbucket = (E + 511) / 512;
        const int ngemm   = 512;
        bucket_gemm_kernel<<<nbucket + ngemm, 512, 0, stream>>>(
            src, dst, work, edge_src, E, nbucket, inputs, W, ybf, N, ngemm);

        aggregate_y4_kernel<<<(N + 3) / 4, 256, 0, stream>>>(
            ybf, edge_src, starts, work, degree, b, out, N);
    } else if (ws_size >= needed_csr && nscan <= 4096) {
        int* starts   = (int*)d_ws;
        int* work     = starts + N;
        int* bsum     = work + N;
        int* edge_src = bsum + 512;

        scan_partial_kernel<<<nscan, 256, 0, stream>>>(degree, bsum, N);
        scan_offsets_kernel<<<nscan, 256, 0, stream>>>(degree, bsum, starts, work, N);
        const int nbucket = (E + 511) / 512;
        bucket_gemm_kernel<<<nbucket, 512, 0, stream>>>(
            src, dst, work, edge_src, E, nbucket, inputs, W, nullptr, 0, 1);
        aggregate_f32_kernel<<<(N + 3) / 4, 256, 0, stream>>>(
            inputs, edge_src, starts, work, degree, out, N);
        transform3_kernel<<<2048, 256, 0, stream>>>(out, W, b, N);
    } else {
        hipMemsetAsync(d_out, 0, (size_t)N * D * sizeof(float), stream);
        const long long total = (long long)E * 32;
        scatter_kernel<<<(int)((total + 255) / 256), 256, 0, stream>>>(inputs, src, dst, out, total);
        divide_kernel<<<(int)(((long long)N * D + 255) / 256), 256, 0, stream>>>(out, degree, N);
        transform3_kernel<<<2048, 256, 0, stream>>>(out, W, b, N);
    }
}